// Round 4
// baseline (21600.853 us; speedup 1.0000x reference)
//
#include <hip/hip_runtime.h>

typedef unsigned short u16;
typedef unsigned int u32;
typedef __bf16 bf16x8 __attribute__((ext_vector_type(8)));
typedef float f32x4 __attribute__((ext_vector_type(4)));

__device__ __forceinline__ u16 f2bf(float f) {
  u32 u = __builtin_bit_cast(u32, f);
  u = (u + 0x7FFFu + ((u >> 16) & 1u)) >> 16;
  return (u16)u;
}

static inline int cdiv(int a, int b) { return (a + b - 1) / b; }

// ---------------------------------------------------------------------------
// K1: fp32 gathered sparse-conv / GEMM with register prefetch.
// out[m,co] = sum_k sum_ci A[nmap[m,k], aoff+ci] * W[k,ci,co].
// nmap==null -> identity.  Tile 128x64, BK=16, 256 thr, 8x4 per thread.
// vec!=0 promises lda%4==0 && aoff%4==0 (float4 A loads legal).
// Used only for dense K=1 projections (residuals, W_sub).
// ---------------------------------------------------------------------------
__global__ __launch_bounds__(256) void k1_conv(
    const float* __restrict__ A, int lda, int aoff, int Cin,
    const int* __restrict__ nmap, int K,
    const float* __restrict__ W, int Cout,
    const float* __restrict__ bias,
    float* __restrict__ out, int ldo, int M, int vec) {
  __shared__ float As[16][128];
  __shared__ float Ws[16][64];
  const int tid = threadIdx.x;
  const int m0 = blockIdx.x * 128;
  const int n0 = blockIdx.y * 64;
  const int tr = (tid >> 4) << 3;   // row frag base 0..120
  const int tc = (tid & 15) << 2;   // col frag base 0..60
  const int r2 = tid & 127;         // staged A row
  const int half = tid >> 7;        // ci half (0/1) -> 8 elems
  const int cw = tid & 63;          // staged W col
  const int cbw = (tid >> 6) << 2;  // staged W ci base
  const int CB = (Cin + 15) >> 4;
  float acc[8][4] = {{0.f}};
  float pa[8], pw[4];
  auto fetch = [&](int k, int cblk) {
    int c0 = cblk * 16;
    int m = m0 + r2;
    int idx = (m < M) ? (nmap ? nmap[(long)m * K + k] : m) : -1;
    const float* src = A + (long)idx * lda + aoff + c0 + half * 8;
    if (vec && idx >= 0 && c0 + half * 8 + 8 <= Cin) {
      float4 v0 = *(const float4*)(src);
      float4 v1 = *(const float4*)(src + 4);
      pa[0] = v0.x; pa[1] = v0.y; pa[2] = v0.z; pa[3] = v0.w;
      pa[4] = v1.x; pa[5] = v1.y; pa[6] = v1.z; pa[7] = v1.w;
    } else {
#pragma unroll
      for (int i = 0; i < 8; ++i) {
        int ci = c0 + half * 8 + i;
        pa[i] = (idx >= 0 && ci < Cin) ? src[i] : 0.f;
      }
    }
    const float* wsrc = W + ((long)k * Cin + c0 + cbw) * Cout + n0 + cw;
#pragma unroll
    for (int i = 0; i < 4; ++i) {
      int ci = c0 + cbw + i;
      pw[i] = (ci < Cin) ? wsrc[(long)i * Cout] : 0.f;
    }
  };
  fetch(0, 0);
  int kc = 0, cc = 0;
  const int T = K * CB;
  for (int t = 0; t < T; ++t) {
#pragma unroll
    for (int i = 0; i < 8; ++i) As[half * 8 + i][r2] = pa[i];
#pragma unroll
    for (int i = 0; i < 4; ++i) Ws[cbw + i][cw] = pw[i];
    __syncthreads();
    int cn = cc + 1, kn = kc;
    if (cn == CB) { cn = 0; kn++; }
    if (kn < K) fetch(kn, cn);
#pragma unroll
    for (int kk = 0; kk < 16; ++kk) {
      float a[8], b[4];
#pragma unroll
      for (int i = 0; i < 8; ++i) a[i] = As[kk][tr + i];
#pragma unroll
      for (int j = 0; j < 4; ++j) b[j] = Ws[kk][tc + j];
#pragma unroll
      for (int i = 0; i < 8; ++i)
#pragma unroll
        for (int j = 0; j < 4; ++j) acc[i][j] += a[i] * b[j];
    }
    __syncthreads();
    cc = cn; kc = kn;
  }
#pragma unroll
  for (int i = 0; i < 8; ++i) {
    int m = m0 + tr + i;
    if (m >= M) continue;
#pragma unroll
    for (int j = 0; j < 4; ++j) {
      int co = n0 + tc + j;
      float v = acc[i][j];
      if (bias) v += bias[co];
      out[(long)m * ldo + co] = v;
    }
  }
}

// ---------------------------------------------------------------------------
// CSR build for pull-style sparse conv (NO atomics anywhere).
// rp[m] = exclusive prefix of per-row valid-neighbor counts (self INCLUDED);
// ent[j] = (src << 5) | k.  3 passes: block scan -> block-offset scan -> fill.
// Requires M <= 262144 (nb <= 1024).
// ---------------------------------------------------------------------------
__global__ __launch_bounds__(256) void k_rp1(
    const int* __restrict__ nmap, int K, int M,
    int* __restrict__ rp, int* __restrict__ bsum) {
  __shared__ int s[256];
  int m = blockIdx.x * 256 + threadIdx.x;
  int c = 0;
  if (m < M) {
    for (int k = 0; k < K; ++k) c += (nmap[(long)m * K + k] >= 0) ? 1 : 0;
  }
  s[threadIdx.x] = c;
  __syncthreads();
  for (int d = 1; d < 256; d <<= 1) {
    int v = (threadIdx.x >= d) ? s[threadIdx.x - d] : 0;
    __syncthreads();
    s[threadIdx.x] += v;
    __syncthreads();
  }
  if (m < M) rp[m] = s[threadIdx.x] - c;  // exclusive within block
  if (threadIdx.x == 255) bsum[blockIdx.x] = s[255];
}

__global__ __launch_bounds__(1024) void k_rp2(
    const int* __restrict__ bsum, int nb,
    int* __restrict__ bofs, int* __restrict__ rpN) {
  __shared__ int s[1024];
  int t = threadIdx.x;
  int v = (t < nb) ? bsum[t] : 0;
  s[t] = v;
  __syncthreads();
  for (int d = 1; d < 1024; d <<= 1) {
    int u = (t >= d) ? s[t - d] : 0;
    __syncthreads();
    s[t] += u;
    __syncthreads();
  }
  if (t < nb) bofs[t] = s[t] - v;  // exclusive block offsets
  if (t == 1023) *rpN = s[1023];   // total pair count -> rp[M]
}

__global__ __launch_bounds__(256) void k_rp3(
    const int* __restrict__ nmap, int K, int M,
    const int* __restrict__ bofs, int* __restrict__ rp,
    int* __restrict__ ent) {
  int m = blockIdx.x * 256 + threadIdx.x;
  if (m >= M) return;
  int base = rp[m] + bofs[blockIdx.x];
  rp[m] = base;
  for (int k = 0; k < K; ++k) {
    int src = nmap[(long)m * K + k];
    if (src >= 0) ent[base++] = (src << 5) | k;
  }
}

// ---------------------------------------------------------------------------
// weight transpose for pull conv: src f32 [K][Cin][64] -> dst f32 [K][64][CIP]
// (co-major; ci zero-padded to CIP, CIP % 4 == 0).  Stays f32: the trunk
// feeds the proxy>0 mask, bf16 weights flip borderline masks (round-3 bug).
// ---------------------------------------------------------------------------
__global__ __launch_bounds__(256) void k_wconvT(
    const float* __restrict__ src, float* __restrict__ dst,
    int K, int Cin, int CIP) {
  long total = (long)K * 64 * CIP;
  long stride = (long)gridDim.x * 256;
  for (long i = (long)blockIdx.x * 256 + threadIdx.x; i < total; i += stride) {
    int ci = (int)(i % CIP);
    long t = i / CIP;
    int co = (int)(t & 63);
    int k = (int)(t >> 6);
    dst[i] = (ci < Cin) ? src[((long)k * Cin + ci) * 64 + co] : 0.f;
  }
}

// ---------------------------------------------------------------------------
// K1P: pull-style sparse conv, NO atomics, f32 end-to-end.  One wave per
// output row, lane = output channel (Cout == 64).  out[m,:] =
// sum_{(k,src) in row m} A[src, aoff:aoff+Cin] @ W[k],
// W staged f32 co-major [k][64][CIP].  A broadcast via __shfl.
// ---------------------------------------------------------------------------
__global__ __launch_bounds__(256) void k1p_conv(
    const float* __restrict__ A, int lda, int aoff, int Cin, int CIP,
    const int* __restrict__ rp, const int* __restrict__ ent,
    const float* __restrict__ WT,
    float* __restrict__ out, int ldo, int M) {
  const int wid = blockIdx.x * 4 + (threadIdx.x >> 6);
  const int lane = threadIdx.x & 63;
  if (wid >= M) return;
  const int j1 = rp[wid + 1];
  float acc = 0.f;
  for (int j = rp[wid]; j < j1; ++j) {
    const int e = ent[j];
    const float* arow = A + (long)(e >> 5) * lda + aoff;
    const float* wrow = WT + (long)(((e & 31) << 6) + lane) * CIP;
    for (int c0 = 0; c0 < CIP; c0 += 64) {
      int cb = Cin - c0; if (cb > 64) cb = 64;   // valid A lanes
      int cp = CIP - c0; if (cp > 64) cp = 64;   // padded W span
      float a = (lane < cb) ? arow[c0 + lane] : 0.f;
      for (int i = 0; i < cp; i += 4) {
        float4 w = *(const float4*)(wrow + c0 + i);
        acc += __shfl(a, i + 0) * w.x;
        acc += __shfl(a, i + 1) * w.y;
        acc += __shfl(a, i + 2) * w.z;
        acc += __shfl(a, i + 3) * w.w;
      }
    }
  }
  out[(long)wid * ldo + lane] = acc;
}

// ---------------------------------------------------------------------------
// K2: bf16 MFMA gathered sparse-conv with register prefetch + N-tiling.
// A bf16 [*, lda]; WT bf16 pre-transposed [k][WTR][CP].
// Block tile 128 x 192 at col offset blockIdx.y*192; 4 waves, each wave
// 4 row-strips x 6 col-tiles of mfma_f32_16x16x32_bf16.
// ---------------------------------------------------------------------------
#define K2_SA 72
__global__ __launch_bounds__(256) void k2_conv(
    const u16* __restrict__ A, int lda,
    const int* __restrict__ nmap, int K,
    const u16* __restrict__ WT, int WTR, int CP,
    int Cout,
    const float* __restrict__ bias,
    float* __restrict__ of, int ldo,
    u16* __restrict__ ob, int ldb,
    int M) {
  __shared__ __align__(16) u16 As[128 * K2_SA];
  __shared__ __align__(16) u16 Ws[192 * K2_SA];
  const int tid = threadIdx.x;
  const int m0 = blockIdx.x * 128;
  const int n0 = blockIdx.y * 192;
  const int lane = tid & 63;
  const int w = tid >> 6;
  const int wr = w >> 1, wc = w & 1;
  const int ln = lane & 15, qd = lane >> 4;
  int Cb = Cout - n0; if (Cb > 192) Cb = 192;
  int NTT = (Cb + 15) >> 4;
  int NTw = NTT - wc * 6;
  if (NTw < 0) NTw = 0;
  if (NTw > 6) NTw = 6;
  const int NSB = CP >> 6;
  const int T = K * NSB;
  const int ar = tid & 127;   // A row owned by this thread
  const int as0 = tid >> 7;   // A slot base: slots as0 + 2*i

  uint4 pa[4], pw[6];
  auto fetch = [&](int k, int sb) {
    int m = m0 + ar;
    int idx = (m < M) ? (nmap ? nmap[(long)m * K + k] : m) : -1;
    const u16* src = A + (long)idx * lda + sb * 64;
#pragma unroll
    for (int i = 0; i < 4; ++i) {
      int s = as0 + 2 * i;
      int ci = sb * 64 + s * 8;
      uint4 v = make_uint4(0u, 0u, 0u, 0u);
      if (idx >= 0 && ci + 8 <= lda) v = *(const uint4*)(src + s * 8);
      pa[i] = v;
    }
    const u16* wk = WT + (long)k * WTR * CP + sb * 64;
#pragma unroll
    for (int i = 0; i < 6; ++i) {
      int id = tid + 256 * i;
      int co = id >> 3, s = id & 7;
      int cog = n0 + co;
      uint4 v = make_uint4(0u, 0u, 0u, 0u);
      if (cog < WTR) v = *(const uint4*)(wk + (long)cog * CP + s * 8);
      pw[i] = v;
    }
  };

  f32x4 acc[4][6];
  f32x4 zero = {0.f, 0.f, 0.f, 0.f};
#pragma unroll
  for (int i = 0; i < 4; ++i)
#pragma unroll
    for (int j = 0; j < 6; ++j) acc[i][j] = zero;

  fetch(0, 0);
  int kc = 0, sc = 0;
  for (int t = 0; t < T; ++t) {
#pragma unroll
    for (int i = 0; i < 4; ++i)
      *(uint4*)&As[ar * K2_SA + (as0 + 2 * i) * 8] = pa[i];
#pragma unroll
    for (int i = 0; i < 6; ++i) {
      int id = tid + 256 * i;
      *(uint4*)&Ws[(id >> 3) * K2_SA + (id & 7) * 8] = pw[i];
    }
    __syncthreads();
    int sn = sc + 1, kn = kc;
    if (sn == NSB) { sn = 0; kn++; }
    if (kn < K) fetch(kn, sn);
    if (NTw > 0) {
#pragma unroll
      for (int ch = 0; ch < 2; ++ch) {
        int koff = ch * 32 + qd * 8;
        bf16x8 a[4];
#pragma unroll
        for (int st = 0; st < 4; ++st)
          a[st] = *(const bf16x8*)&As[(wr * 64 + st * 16 + ln) * K2_SA + koff];
#pragma unroll
        for (int nt = 0; nt < 6; ++nt) {
          if (nt < NTw) {
            bf16x8 b = *(const bf16x8*)&Ws[(wc * 96 + nt * 16 + ln) * K2_SA + koff];
#pragma unroll
            for (int st = 0; st < 4; ++st)
              acc[st][nt] = __builtin_amdgcn_mfma_f32_16x16x32_bf16(a[st], b, acc[st][nt], 0, 0, 0);
          }
        }
      }
    }
    __syncthreads();
    sc = sn; kc = kn;
  }
#pragma unroll
  for (int nt = 0; nt < 6; ++nt) {
    if (nt >= NTw) continue;
    int col = n0 + wc * 96 + nt * 16 + ln;
    if (col >= Cout) continue;
    float bv = bias ? bias[col] : 0.f;
#pragma unroll
    for (int st = 0; st < 4; ++st) {
#pragma unroll
      for (int i = 0; i < 4; ++i) {
        int m = m0 + wr * 64 + st * 16 + qd * 4 + i;
        if (m < M) {
          float v = acc[st][nt][i] + bv;
          if (of) of[(long)m * ldo + col] = v;
          if (ob) ob[(long)m * ldb + col] = f2bf(v);
        }
      }
    }
  }
}

// ---------------------------------------------------------------------------
// stats: per-(batch,channel) sum / sumsq (+count) for instance norm.
// ---------------------------------------------------------------------------
__global__ __launch_bounds__(256) void k_stats(
    const float* __restrict__ x, int ld, int M, int C,
    const int* __restrict__ bidx, float* __restrict__ st) {
  __shared__ float ssum[2][192];
  __shared__ float ssq[2][192];
  __shared__ float scnt[2];
  for (int i = threadIdx.x; i < 384; i += 256) {
    ((float*)ssum)[i] = 0.f;
    ((float*)ssq)[i] = 0.f;
  }
  if (threadIdx.x < 2) scnt[threadIdx.x] = 0.f;
  __syncthreads();
  const int CV = C >> 2;
  const int RG = 256 / CV;
  const int tid = threadIdx.x;
  const int c4 = tid % CV;
  const int rg = tid / CV;
  int rpb = (M + gridDim.x - 1) / gridDim.x;
  int r0 = blockIdx.x * rpb;
  int r1 = r0 + rpb;
  if (r1 > M) r1 = M;
  if (rg < RG) {
    float s0[4] = {0.f, 0.f, 0.f, 0.f}, q0[4] = {0.f, 0.f, 0.f, 0.f};
    float s1[4] = {0.f, 0.f, 0.f, 0.f}, q1[4] = {0.f, 0.f, 0.f, 0.f};
    float n0 = 0.f, n1 = 0.f;
    for (int rr = r0 + rg; rr < r1; rr += RG) {
      int b = bidx[rr];
      float4 v = *(const float4*)&x[(long)rr * ld + c4 * 4];
      const float* vp = &v.x;
      if (b == 0) {
#pragma unroll
        for (int j = 0; j < 4; ++j) { s0[j] += vp[j]; q0[j] += vp[j] * vp[j]; }
        n0 += 1.f;
      } else {
#pragma unroll
        for (int j = 0; j < 4; ++j) { s1[j] += vp[j]; q1[j] += vp[j] * vp[j]; }
        n1 += 1.f;
      }
    }
#pragma unroll
    for (int j = 0; j < 4; ++j) {
      if (s0[j] != 0.f || q0[j] != 0.f) {
        atomicAdd(&ssum[0][c4 * 4 + j], s0[j]);
        atomicAdd(&ssq[0][c4 * 4 + j], q0[j]);
      }
      if (s1[j] != 0.f || q1[j] != 0.f) {
        atomicAdd(&ssum[1][c4 * 4 + j], s1[j]);
        atomicAdd(&ssq[1][c4 * 4 + j], q1[j]);
      }
    }
    if (c4 == 0) {
      if (n0 != 0.f) atomicAdd(&scnt[0], n0);
      if (n1 != 0.f) atomicAdd(&scnt[1], n1);
    }
  }
  __syncthreads();
  for (int i = threadIdx.x; i < C; i += 256) {
    if (ssum[0][i] != 0.f || ssq[0][i] != 0.f) {
      atomicAdd(&st[i], ssum[0][i]);
      atomicAdd(&st[C + i], ssq[0][i]);
    }
    if (ssum[1][i] != 0.f || ssq[1][i] != 0.f) {
      atomicAdd(&st[2 * C + i], ssum[1][i]);
      atomicAdd(&st[3 * C + i], ssq[1][i]);
    }
  }
  if (threadIdx.x == 0) {
    if (scnt[0] != 0.f) atomicAdd(&st[4 * C], scnt[0]);
    if (scnt[1] != 0.f) atomicAdd(&st[4 * C + 1], scnt[1]);
  }
}

// ---------------------------------------------------------------------------
// apply: v = (x - mean)*rsqrt(var+eps) [+ res] [relu] -> optional f32 / bf16
// ---------------------------------------------------------------------------
__global__ __launch_bounds__(256) void k_apply(
    const float* __restrict__ x, int ldx, int M, int C,
    const int* __restrict__ bidx, const float* __restrict__ st,
    const float* __restrict__ res, int ldr, int relu,
    float* __restrict__ of, int ldo, u16* __restrict__ ob, int ldb) {
  __shared__ float mean_s[2][192];
  __shared__ float inv_s[2][192];
  for (int j = threadIdx.x; j < 2 * C; j += 256) {
    int b = (j >= C) ? 1 : 0;
    int c = j - b * C;
    float cnt = st[4 * C + b];
    float mean = st[b * 2 * C + c] / cnt;
    float var = st[b * 2 * C + C + c] / cnt - mean * mean;
    mean_s[b][c] = mean;
    inv_s[b][c] = 1.f / sqrtf(fmaxf(var, 0.f) + 1e-5f);
  }
  __syncthreads();
  const int CV = C >> 2;
  long total = (long)M * CV;
  long stride = (long)gridDim.x * 256;
  for (long i = (long)blockIdx.x * 256 + threadIdx.x; i < total; i += stride) {
    int rr = (int)(i / CV);
    int c4 = (int)(i - (long)rr * CV);
    int b = bidx[rr];
    float4 v = *(const float4*)&x[(long)rr * ldx + c4 * 4];
    const float* vp = &v.x;
    float o[4];
#pragma unroll
    for (int j = 0; j < 4; ++j) {
      int c = c4 * 4 + j;
      o[j] = (vp[j] - mean_s[b][c]) * inv_s[b][c];
    }
    if (res) {
      float4 rv = *(const float4*)&res[(long)rr * ldr + c4 * 4];
      const float* rp = &rv.x;
#pragma unroll
      for (int j = 0; j < 4; ++j) o[j] += rp[j];
    }
    if (relu) {
#pragma unroll
      for (int j = 0; j < 4; ++j) o[j] = fmaxf(o[j], 0.f);
    }
    if (of) {
      float4 ov = make_float4(o[0], o[1], o[2], o[3]);
      *(float4*)&of[(long)rr * ldo + c4 * 4] = ov;
    }
    if (ob) {
      ushort4 u;
      u.x = f2bf(o[0]); u.y = f2bf(o[1]); u.z = f2bf(o[2]); u.w = f2bf(o[3]);
      *(ushort4*)&ob[(long)rr * ldb + c4 * 4] = u;
    }
  }
}

// proxy = sparse @ W_occ + b_occ ; mask = proxy > 0 ; sp = mask ? sparse : 0
__global__ __launch_bounds__(256) void k_mask(
    const float* __restrict__ sp, const float* __restrict__ Wocc,
    const float* __restrict__ bocc, float* __restrict__ proxy,
    float* __restrict__ catf, u16* __restrict__ catb, int M) {
  int r = blockIdx.x * 4 + (threadIdx.x >> 6);
  int lane = threadIdx.x & 63;
  if (r >= M) return;
  float v0 = sp[(long)r * 128 + lane];
  float v1 = sp[(long)r * 128 + 64 + lane];
  float s = v0 * Wocc[lane] + v1 * Wocc[64 + lane];
  for (int off = 32; off > 0; off >>= 1) s += __shfl_down(s, off);
  s = __shfl(s, 0);
  float p = s + bocc[0];
  if (lane == 0) proxy[r] = p;
  bool m = p > 0.0f;
  float w0 = m ? v0 : 0.f, w1 = m ? v1 : 0.f;
  catf[(long)r * 192 + 64 + lane] = w0;
  catf[(long)r * 192 + 128 + lane] = w1;
  catb[(long)r * 192 + 64 + lane] = f2bf(w0);
  catb[(long)r * 192 + 128 + lane] = f2bf(w1);
}

// copy cat -> full[:,0:192] and zero full[:,229:232]
__global__ __launch_bounds__(256) void k_full(
    const u16* __restrict__ catb, u16* __restrict__ full, int M) {
  long total = (long)M * 195;
  long stride = (long)gridDim.x * 256;
  for (long i = (long)blockIdx.x * 256 + threadIdx.x; i < total; i += stride) {
    int r = (int)(i / 195);
    int j = (int)(i - (long)r * 195);
    if (j < 192)
      full[(long)r * 232 + j] = catb[(long)r * 192 + j];
    else
      full[(long)r * 232 + 229 + (j - 192)] = 0;
  }
}

// weight convert: src f32 [K][Cin][Cout] -> dst bf16 transposed [K][WTR][CP]
__global__ __launch_bounds__(256) void k_wconv(
    const float* __restrict__ src, u16* __restrict__ dst,
    int K, int Cin, int Cout, int WTR, int CP) {
  long total = (long)K * WTR * CP;
  long stride = (long)gridDim.x * 256;
  for (long i = (long)blockIdx.x * 256 + threadIdx.x; i < total; i += stride) {
    int ci = (int)(i % CP);
    long t = i / CP;
    int co = (int)(t % WTR);
    int k = (int)(t / WTR);
    float v = 0.f;
    if (ci < Cin && co < Cout) v = src[((long)k * Cin + ci) * Cout + co];
    dst[i] = f2bf(v);
  }
}

// ---------------------------------------------------------------------------
extern "C" void kernel_launch(void* const* d_in, const int* in_sizes, int n_in,
                              void* d_out, int out_size, void* d_ws, size_t ws_size,
                              hipStream_t stream) {
  const float* features = (const float*)d_in[0];
  const int* nmap1 = (const int*)d_in[1];
  const int* cmap = (const int*)d_in[2];
  const int* nmap2 = (const int*)d_in[3];
  const int* b1 = (const int*)d_in[4];
  const int* b2 = (const int*)d_in[5];
  const int* b3 = (const int*)d_in[6];
  const float* W_d1 = (const float*)d_in[7];
  const float* W_d2 = (const float*)d_in[8];
  const float* Wd_d = (const float*)d_in[9];
  const float* W_f1 = (const float*)d_in[11];
  const float* W_f2 = (const float*)d_in[12];
  const float* Wd_f = (const float*)d_in[13];
  const float* W_i1 = (const float*)d_in[15];
  const float* W_i2 = (const float*)d_in[16];
  const float* Wd_i = (const float*)d_in[17];
  const float* W_e1a = (const float*)d_in[19];
  const float* W_e1b = (const float*)d_in[20];
  const float* W_ed = (const float*)d_in[21];
  const float* W_e2a = (const float*)d_in[23];
  const float* W_e2b = (const float*)d_in[24];
  const float* W_sub = (const float*)d_in[25];
  const float* b_sub = (const float*)d_in[26];
  const float* W_occ = (const float*)d_in[27];
  const float* b_occ = (const float*)d_in[28];
  const float* W_pi1 = (const float*)d_in[29];
  const float* W_pi2 = (const float*)d_in[30];
  const float* W_pi3 = (const float*)d_in[31];
  const float* b_pi3 = (const float*)d_in[32];
  const float* W_ps1 = (const float*)d_in[33];
  const float* W_ps2 = (const float*)d_in[34];
  const float* W_ps3 = (const float*)d_in[35];
  const float* b_ps3 = (const float*)d_in[36];
  const float* W_t = (const float*)d_in[37];

  const int N1 = in_sizes[4];
  const int N2 = in_sizes[5];

  // ---- workspace layout ----
  char* base = (char*)d_ws;
  size_t off = 0;
  auto alloc = [&](size_t bytes) -> void* {
    void* r = base + off;
    off += (bytes + 255) & ~(size_t)255;
    return r;
  };
  float* x = (float*)alloc((size_t)N1 * 192 * 4);        // fine features; aliased by cat_f32
  float* T = (float*)alloc((size_t)N1 * 256 * 4);        // trunk temps / t192
  float* Bq1 = T;
  float* Bq2 = T + (size_t)N1 * 64;
  float* Bq3 = T + (size_t)N1 * 128;
  float* Bq4 = T + (size_t)N1 * 192;
  float* t192 = T;
  u16* catb = (u16*)alloc((size_t)N2 * 192 * 2);
  u16* hb = (u16*)alloc((size_t)N2 * 192 * 2);
  u16* pib = (u16*)alloc((size_t)N2 * 192 * 2);
  u16* fullb = (u16*)alloc((size_t)N2 * 232 * 2);
  float* spf = (float*)alloc((size_t)N2 * 128 * 4);
  u16* WTpi1 = (u16*)alloc((size_t)27 * 192 * 192 * 2);
  u16* WTpi2 = (u16*)alloc((size_t)27 * 192 * 192 * 2);
  u16* WTps1 = (u16*)alloc((size_t)27 * 192 * 192 * 2);
  u16* WTps2 = (u16*)alloc((size_t)27 * 192 * 192 * 2);
  u16* WTpi3 = (u16*)alloc((size_t)27 * 32 * 192 * 2);
  u16* WTps3 = (u16*)alloc((size_t)27 * 32 * 192 * 2);
  u16* WTt = (u16*)alloc((size_t)8 * 64 * 256 * 2);
  float* stats = (float*)alloc((size_t)19 * 772 * 4);
  // CSR (pull) structures
  int* rp1 = (int*)alloc((size_t)(N1 + 1) * 4);
  int* rpc = (int*)alloc((size_t)(N2 + 1) * 4);
  int* rp2 = (int*)alloc((size_t)(N2 + 1) * 4);
  int* e1 = (int*)alloc((size_t)N1 * 27 * 4);
  int* ec = (int*)alloc((size_t)N2 * 8 * 4);
  int* e2 = (int*)alloc((size_t)N2 * 27 * 4);
  int* bscr = (int*)alloc((size_t)2048 * 4);  // bsum[1024] + bofs[1024]
  // pull-conv f32 transposed weights [K][64][CIP]  (f32: proxy-path precision)
  float* WTd1 = (float*)alloc((size_t)27 * 64 * 4 * 4);
  float* WTf1 = (float*)alloc((size_t)27 * 64 * 80 * 4);
  float* WTi1 = (float*)alloc((size_t)27 * 64 * 20 * 4);
  float* WTd2 = (float*)alloc((size_t)27 * 64 * 64 * 4);
  float* WTf2 = (float*)alloc((size_t)27 * 64 * 64 * 4);
  float* WTi2 = (float*)alloc((size_t)27 * 64 * 64 * 4);
  float* WTe1a = (float*)alloc((size_t)8 * 64 * 192 * 4);
  float* WTed = (float*)alloc((size_t)8 * 64 * 192 * 4);
  float* WTe1b = (float*)alloc((size_t)27 * 64 * 64 * 4);
  float* WTe2a = (float*)alloc((size_t)27 * 64 * 64 * 4);
  float* WTe2b = (float*)alloc((size_t)27 * 64 * 64 * 4);
  if (off > ws_size) return;  // workspace too small: bail (will fail loudly)

  float* catf = x;  // alias: x is dead once encoder residuals are built
  float* dout = (float*)d_out;
  float* out0 = dout;
  float* proxyp = dout + (size_t)N2 * 512;
  float* pip = proxyp + N2;
  float* psp = pip + (size_t)N2 * 17;

  hipMemsetAsync(stats, 0, (size_t)19 * 772 * 4, stream);

  // ---- CSR build (pull; self offsets included; no atomics) ----
  auto csr = [&](const int* nm, int Mrows, int K, int* rp, int* ent) {
    int nb = cdiv(Mrows, 256);  // requires Mrows <= 262144
    k_rp1<<<nb, 256, 0, stream>>>(nm, K, Mrows, rp, bscr);
    k_rp2<<<1, 1024, 0, stream>>>(bscr, nb, bscr + 1024, rp + Mrows);
    k_rp3<<<nb, 256, 0, stream>>>(nm, K, Mrows, bscr + 1024, rp, ent);
  };
  csr(nmap1, N1, 27, rp1, e1);
  csr(cmap, N2, 8, rpc, ec);
  csr(nmap2, N2, 27, rp2, e2);

  // weight conversion: bf16 heads (row-major co x ci) ...
  k_wconv<<<256, 256, 0, stream>>>(W_pi1, WTpi1, 27, 192, 192, 192, 192);
  k_wconv<<<256, 256, 0, stream>>>(W_pi2, WTpi2, 27, 192, 192, 192, 192);
  k_wconv<<<256, 256, 0, stream>>>(W_ps1, WTps1, 27, 192, 192, 192, 192);
  k_wconv<<<256, 256, 0, stream>>>(W_ps2, WTps2, 27, 192, 192, 192, 192);
  k_wconv<<<256, 256, 0, stream>>>(W_pi3, WTpi3, 27, 192, 17, 32, 192);
  k_wconv<<<256, 256, 0, stream>>>(W_ps3, WTps3, 27, 192, 20, 32, 192);
  k_wconv<<<256, 256, 0, stream>>>(W_t, WTt, 8, 229, 64, 64, 256);
  // ... and pull-conv transposed weights (f32 co-major, CIP padded to 4)
  k_wconvT<<<64, 256, 0, stream>>>(W_d1, WTd1, 27, 2, 4);
  k_wconvT<<<256, 256, 0, stream>>>(W_f1, WTf1, 27, 80, 80);
  k_wconvT<<<64, 256, 0, stream>>>(W_i1, WTi1, 27, 17, 20);
  k_wconvT<<<256, 256, 0, stream>>>(W_d2, WTd2, 27, 64, 64);
  k_wconvT<<<256, 256, 0, stream>>>(W_f2, WTf2, 27, 64, 64);
  k_wconvT<<<256, 256, 0, stream>>>(W_i2, WTi2, 27, 64, 64);
  k_wconvT<<<256, 256, 0, stream>>>(W_e1a, WTe1a, 8, 192, 192);
  k_wconvT<<<256, 256, 0, stream>>>(W_ed, WTed, 8, 192, 192);
  k_wconvT<<<256, 256, 0, stream>>>(W_e1b, WTe1b, 27, 64, 64);
  k_wconvT<<<256, 256, 0, stream>>>(W_e2a, WTe2a, 27, 64, 64);
  k_wconvT<<<256, 256, 0, stream>>>(W_e2b, WTe2b, 27, 64, 64);

  const int SG = 1024;   // stats grid
  const int AG = 1024;   // apply grid
  const int PG1 = cdiv(N1, 4);  // pull grid fine (wave per row)
  const int PG2 = cdiv(N2, 4);  // pull grid coarse
  int slot = 0;
  struct Br { int aoff, Cin, CIP; const float *WT1, *WT2, *Wd; };
  Br brs[3] = {{0, 2, 4, WTd1, WTd2, Wd_d},
               {2, 80, 80, WTf1, WTf2, Wd_f},
               {82, 17, 20, WTi1, WTi2, Wd_i}};

  // ---- fine branches (fp32 trunk, pull sparse conv) ----
  for (int b = 0; b < 3; ++b) {
    const int Cin = brs[b].Cin;
    // dense residual: inorm(f @ Wd)  (bias is a no-op under inorm)
    k1_conv<<<dim3(cdiv(N1, 128), 1), 256, 0, stream>>>(
        features, 99, brs[b].aoff, Cin, nullptr, 1, brs[b].Wd, 64, nullptr, Bq1, 64, N1, 0);
    k_stats<<<SG, 256, 0, stream>>>(Bq1, 64, N1, 64, b1, stats + slot * 772);
    k_apply<<<AG, 256, 0, stream>>>(Bq1, 64, N1, 64, b1, stats + slot * 772,
                                    nullptr, 0, 0, Bq3, 64, nullptr, 0);
    slot++;
    // conv1 (pull, incl. self) + inorm + relu
    k1p_conv<<<PG1, 256, 0, stream>>>(
        features, 99, brs[b].aoff, Cin, brs[b].CIP, rp1, e1, brs[b].WT1, Bq1, 64, N1);
    k_stats<<<SG, 256, 0, stream>>>(Bq1, 64, N1, 64, b1, stats + slot * 772);
    k_apply<<<AG, 256, 0, stream>>>(Bq1, 64, N1, 64, b1, stats + slot * 772,
                                    nullptr, 0, 1, Bq2, 64, nullptr, 0);
    slot++;
    // conv2 (pull) + inorm + res + relu -> x[:, b*64 : b*64+64]
    k1p_conv<<<PG1, 256, 0, stream>>>(
        Bq2, 64, 0, 64, 64, rp1, e1, brs[b].WT2, Bq4, 64, N1);
    k_stats<<<SG, 256, 0, stream>>>(Bq4, 64, N1, 64, b1, stats + slot * 772);
    k_apply<<<AG, 256, 0, stream>>>(Bq4, 64, N1, 64, b1, stats + slot * 772,
                                    Bq3, 64, 1, x + b * 64, 192, nullptr, 0);
    slot++;
  }

  // ---- encoder (fp32 trunk, pull) ----
  // e1a: downsample conv (cmap) + inorm + relu -> Bq2
  k1p_conv<<<PG2, 256, 0, stream>>>(x, 192, 0, 192, 192, rpc, ec, WTe1a, Bq1, 64, N2);
  k_stats<<<SG, 256, 0, stream>>>(Bq1, 64, N2, 64, b2, stats + slot * 772);
  k_apply<<<AG, 256, 0, stream>>>(Bq1, 64, N2, 64, b2, stats + slot * 772,
                                  nullptr, 0, 1, Bq2, 64, nullptr, 0);
  slot++;
  // e1b conv -> Bq4 (norm applied later with res)
  k1p_conv<<<PG2, 256, 0, stream>>>(Bq2, 64, 0, 64, 64, rp2, e2, WTe1b, Bq4, 64, N2);
  k_stats<<<SG, 256, 0, stream>>>(Bq4, 64, N2, 64, b2, stats + slot * 772);
  int sl_e1b = slot; slot++;
  // ed: residual downsample conv + inorm (b_ed no-op) -> Bq3
  k1p_conv<<<PG2, 256, 0, stream>>>(x, 192, 0, 192, 192, rpc, ec, WTed, Bq1, 64, N2);
  k_stats<<<SG, 256, 0, stream>>>(Bq1, 64, N2, 64, b2, stats + slot * 772);
  k_apply<<<AG, 256, 0, stream>>>(Bq1, 64, N2, 64, b2, stats + slot * 772,
                                  nullptr, 0, 0, Bq3, 64, nullptr, 0);
  slot++;
  // enc_pre = relu(inorm(e1b) + res) -> Bq2
  k_apply<<<AG, 256, 0, stream>>>(Bq4, 64, N2, 64, b2, stats + sl_e1b * 772,
                                  Bq3, 64, 1, Bq2, 64, nullptr, 0);
  // _sbb(enc_pre): e2a conv (pull) + inorm + relu -> Bq3
  k1p_conv<<<PG2, 256, 0, stream>>>(Bq2, 64, 0, 64, 64, rp2, e2, WTe2a, Bq1, 64, N2);
  k_stats<<<SG, 256, 0, stream>>>(Bq1, 64, N2, 64, b2, stats + slot * 772);
  k_apply<<<AG, 256, 0, stream>>>(Bq1, 64, N2, 64, b2, stats + slot * 772,
                                  nullptr, 0, 1, Bq3, 64, nullptr, 0);
  slot++;
  // e2b conv (pull) + inorm + res(enc_pre) + relu -> enc (cat cols 0..63)
  k1p_conv<<<PG2, 256, 0, stream>>>(Bq3, 64, 0, 64, 64, rp2, e2, WTe2b, Bq4, 64, N2);
  k_stats<<<SG, 256, 0, stream>>>(Bq4, 64, N2, 64, b2, stats + slot * 772);
  k_apply<<<AG, 256, 0, stream>>>(Bq4, 64, N2, 64, b2, stats + slot * 772,
                                  Bq2, 64, 1, catf, 192, catb, 192);
  slot++;

  // ---- sparse / proxy / mask (fp32) ----
  k1_conv<<<dim3(cdiv(N2, 128), 2), 256, 0, stream>>>(
      catf, 192, 0, 64, nullptr, 1, W_sub, 128, b_sub, spf, 128, N2, 1);
  k_mask<<<cdiv(N2, 4), 256, 0, stream>>>(spf, W_occ, b_occ, proxyp, catf, catb, N2);
  k_full<<<1024, 256, 0, stream>>>(catb, fullb, N2);

  // ---- heads (bf16 MFMA, dense over 27 this round) ----
  const u16* WT1[2] = {WTpi1, WTps1};
  const u16* WT2[2] = {WTpi2, WTps2};
  const u16* WT3[2] = {WTpi3, WTps3};
  const float* b3v[2] = {b_pi3, b_ps3};
  float* outh[2] = {pip, psp};
  int co3[2] = {17, 20};
  int ld3[2] = {17, 20};
  int foff[2] = {192, 209};
  for (int h = 0; h < 2; ++h) {
    k2_conv<<<dim3(cdiv(N2, 128), 1), 256, 0, stream>>>(
        catb, 192, nmap2, 27, WT1[h], 192, 192, 192, nullptr, t192, 192, nullptr, 0, N2);
    k_stats<<<SG, 256, 0, stream>>>(t192, 192, N2, 192, b2, stats + slot * 772);
    k_apply<<<AG, 256, 0, stream>>>(t192, 192, N2, 192, b2, stats + slot * 772,
                                    nullptr, 0, 1, nullptr, 0, hb, 192);
    slot++;
    k2_conv<<<dim3(cdiv(N2, 128), 1), 256, 0, stream>>>(
        hb, 192, nmap2, 27, WT2[h], 192, 192, 192, nullptr, t192, 192, nullptr, 0, N2);
    k_stats<<<SG, 256, 0, stream>>>(t192, 192, N2, 192, b2, stats + slot * 772);
    k_apply<<<AG, 256, 0, stream>>>(t192, 192, N2, 192, b2, stats + slot * 772,
                                    catf, 192, 1, nullptr, 0, pib, 192);
    slot++;
    k2_conv<<<dim3(cdiv(N2, 128), 1), 256, 0, stream>>>(
        pib, 192, nmap2, 27, WT3[h], 32, 192, co3[h], b3v[h],
        outh[h], ld3[h], fullb + foff[h], 232, N2);
  }

  // ---- final einsum as ONE GEMM: out[m, k*64+co] = full[m] . W_t[k][:,co] ----
  k2_conv<<<dim3(cdiv(N2, 128), 3), 256, 0, stream>>>(
      fullb, 232, nullptr, 1, WTt, 512, 256, 512, nullptr,
      out0, 512, nullptr, 0, N2);

  // final inorm + relu over (N2*8, 64) rows with b3, in place in d_out
  k_stats<<<SG, 256, 0, stream>>>(out0, 64, N2 * 8, 64, b3, stats + slot * 772);
  k_apply<<<AG, 256, 0, stream>>>(out0, 64, N2 * 8, 64, b3, stats + slot * 772,
                                  nullptr, 0, 1, out0, 64, nullptr, 0);
}

// Round 5
// 6002.298 us; speedup vs baseline: 3.5988x; 3.5988x over previous
//
#include <hip/hip_runtime.h>

typedef unsigned short u16;
typedef unsigned int u32;
typedef __bf16 bf16x8 __attribute__((ext_vector_type(8)));
typedef float f32x4 __attribute__((ext_vector_type(4)));

__device__ __forceinline__ u16 f2bf(float f) {
  u32 u = __builtin_bit_cast(u32, f);
  u = (u + 0x7FFFu + ((u >> 16) & 1u)) >> 16;
  return (u16)u;
}

static inline int cdiv(int a, int b) { return (a + b - 1) / b; }

// ---------------------------------------------------------------------------
// K1: fp32 dense GEMM (K=1 projections: residuals, W_sub).
// ---------------------------------------------------------------------------
__global__ __launch_bounds__(256) void k1_conv(
    const float* __restrict__ A, int lda, int aoff, int Cin,
    const int* __restrict__ nmap, int K,
    const float* __restrict__ W, int Cout,
    const float* __restrict__ bias,
    float* __restrict__ out, int ldo, int M, int vec) {
  __shared__ float As[16][128];
  __shared__ float Ws[16][64];
  const int tid = threadIdx.x;
  const int m0 = blockIdx.x * 128;
  const int n0 = blockIdx.y * 64;
  const int tr = (tid >> 4) << 3;
  const int tc = (tid & 15) << 2;
  const int r2 = tid & 127;
  const int half = tid >> 7;
  const int cw = tid & 63;
  const int cbw = (tid >> 6) << 2;
  const int CB = (Cin + 15) >> 4;
  float acc[8][4] = {{0.f}};
  float pa[8], pw[4];
  auto fetch = [&](int k, int cblk) {
    int c0 = cblk * 16;
    int m = m0 + r2;
    int idx = (m < M) ? (nmap ? nmap[(long)m * K + k] : m) : -1;
    const float* src = A + (long)idx * lda + aoff + c0 + half * 8;
    if (vec && idx >= 0 && c0 + half * 8 + 8 <= Cin) {
      float4 v0 = *(const float4*)(src);
      float4 v1 = *(const float4*)(src + 4);
      pa[0] = v0.x; pa[1] = v0.y; pa[2] = v0.z; pa[3] = v0.w;
      pa[4] = v1.x; pa[5] = v1.y; pa[6] = v1.z; pa[7] = v1.w;
    } else {
#pragma unroll
      for (int i = 0; i < 8; ++i) {
        int ci = c0 + half * 8 + i;
        pa[i] = (idx >= 0 && ci < Cin) ? src[i] : 0.f;
      }
    }
    const float* wsrc = W + ((long)k * Cin + c0 + cbw) * Cout + n0 + cw;
#pragma unroll
    for (int i = 0; i < 4; ++i) {
      int ci = c0 + cbw + i;
      pw[i] = (ci < Cin) ? wsrc[(long)i * Cout] : 0.f;
    }
  };
  fetch(0, 0);
  int kc = 0, cc = 0;
  const int T = K * CB;
  for (int t = 0; t < T; ++t) {
#pragma unroll
    for (int i = 0; i < 8; ++i) As[half * 8 + i][r2] = pa[i];
#pragma unroll
    for (int i = 0; i < 4; ++i) Ws[cbw + i][cw] = pw[i];
    __syncthreads();
    int cn = cc + 1, kn = kc;
    if (cn == CB) { cn = 0; kn++; }
    if (kn < K) fetch(kn, cn);
#pragma unroll
    for (int kk = 0; kk < 16; ++kk) {
      float a[8], b[4];
#pragma unroll
      for (int i = 0; i < 8; ++i) a[i] = As[kk][tr + i];
#pragma unroll
      for (int j = 0; j < 4; ++j) b[j] = Ws[kk][tc + j];
#pragma unroll
      for (int i = 0; i < 8; ++i)
#pragma unroll
        for (int j = 0; j < 4; ++j) acc[i][j] += a[i] * b[j];
    }
    __syncthreads();
    cc = cn; kc = kn;
  }
#pragma unroll
  for (int i = 0; i < 8; ++i) {
    int m = m0 + tr + i;
    if (m >= M) continue;
#pragma unroll
    for (int j = 0; j < 4; ++j) {
      int co = n0 + tc + j;
      float v = acc[i][j];
      if (bias) v += bias[co];
      out[(long)m * ldo + co] = v;
    }
  }
}

// ---------------------------------------------------------------------------
// Sparse-conv index build (all offsets incl. self; no data atomics).
// Per map meta (256 ints): cnt[0..31], base[32..64], tileBase[65..97],
// cur[98..129].  dst[gp]=row m (k-sorted lists, 128-row tiles);
// rp[m]..rp[m+1] -> rmap entries = pair positions of row m.
// ---------------------------------------------------------------------------
__global__ __launch_bounds__(256) void k_cnt(
    const int* __restrict__ nmap, int K, int M, int* __restrict__ cnt) {
  __shared__ int lc[32];
  if (threadIdx.x < 32) lc[threadIdx.x] = 0;
  __syncthreads();
  int m = blockIdx.x * 256 + threadIdx.x;
  if (m < M)
    for (int k = 0; k < K; ++k)
      if (nmap[(long)m * K + k] >= 0) atomicAdd(&lc[k], 1);
  __syncthreads();
  if (threadIdx.x < K && lc[threadIdx.x]) atomicAdd(&cnt[threadIdx.x], lc[threadIdx.x]);
}

__global__ void k_cscan(const int* __restrict__ cnt, int K,
                        int* __restrict__ base, int* __restrict__ tileBase,
                        int* __restrict__ cur) {
  if (threadIdx.x == 0 && blockIdx.x == 0) {
    int b = 0, tb = 0;
    for (int k = 0; k < K; ++k) {
      base[k] = b; tileBase[k] = tb;
      b += cnt[k]; tb += (cnt[k] + 127) >> 7;
      cur[k] = 0;
    }
    base[K] = b; tileBase[K] = tb;
  }
}

// row-count block scan (rp exclusive within block; bsum per block)
__global__ __launch_bounds__(256) void k_rp1(
    const int* __restrict__ nmap, int K, int M,
    int* __restrict__ rp, int* __restrict__ bsum) {
  __shared__ int s[256];
  int m = blockIdx.x * 256 + threadIdx.x;
  int c = 0;
  if (m < M) {
    for (int k = 0; k < K; ++k) c += (nmap[(long)m * K + k] >= 0) ? 1 : 0;
  }
  s[threadIdx.x] = c;
  __syncthreads();
  for (int d = 1; d < 256; d <<= 1) {
    int v = (threadIdx.x >= d) ? s[threadIdx.x - d] : 0;
    __syncthreads();
    s[threadIdx.x] += v;
    __syncthreads();
  }
  if (m < M) rp[m] = s[threadIdx.x] - c;
  if (threadIdx.x == 255) bsum[blockIdx.x] = s[255];
}

__global__ __launch_bounds__(1024) void k_rp2(
    const int* __restrict__ bsum, int nb,
    int* __restrict__ bofs, int* __restrict__ rpN) {
  __shared__ int s[1024];
  int t = threadIdx.x;
  int v = (t < nb) ? bsum[t] : 0;
  s[t] = v;
  __syncthreads();
  for (int d = 1; d < 1024; d <<= 1) {
    int u = (t >= d) ? s[t - d] : 0;
    __syncthreads();
    s[t] += u;
    __syncthreads();
  }
  if (t < nb) bofs[t] = s[t] - v;
  if (t == 1023) *rpN = s[1023];
}

__global__ __launch_bounds__(256) void k_fill(
    const int* __restrict__ nmap, int K, int M,
    const int* __restrict__ base, int* __restrict__ gcur,
    const int* __restrict__ bofs,
    int* __restrict__ rp, int* __restrict__ dst, int* __restrict__ rmap) {
  __shared__ int lc[32], lb[32];
  if (threadIdx.x < 32) lc[threadIdx.x] = 0;
  __syncthreads();
  int m = blockIdx.x * 256 + threadIdx.x;
  if (m < M)
    for (int k = 0; k < K; ++k)
      if (nmap[(long)m * K + k] >= 0) atomicAdd(&lc[k], 1);
  __syncthreads();
  if (threadIdx.x < 32) {
    int c = (threadIdx.x < K) ? lc[threadIdx.x] : 0;
    lb[threadIdx.x] = c ? atomicAdd(&gcur[threadIdx.x], c) : 0;
  }
  __syncthreads();
  if (threadIdx.x < 32) lc[threadIdx.x] = 0;
  __syncthreads();
  if (m < M) {
    int rbase = rp[m] + bofs[blockIdx.x];
    rp[m] = rbase;
    for (int k = 0; k < K; ++k)
      if (nmap[(long)m * K + k] >= 0) {
        int lp = atomicAdd(&lc[k], 1);
        int gp = base[k] + lb[k] + lp;
        dst[gp] = m;
        rmap[rbase++] = gp;
      }
  }
}

// ---------------------------------------------------------------------------
// K1G: per-offset gather-GEMM into pair-indexed partial buffer (NO atomics).
// Grid-strided over 128-row tiles of the k-sorted pair lists; tile has ONE k.
// part[pairIdx][0:64] = A[nmap[dst[pairIdx],k]] @ W[k].  Coalesced stores.
// ---------------------------------------------------------------------------
__global__ __launch_bounds__(256) void k1g_conv(
    const float* __restrict__ A, int lda, int aoff, int Cin,
    const int* __restrict__ nmap, int K,
    const int* __restrict__ dst, const int* __restrict__ base,
    const int* __restrict__ tileBase,
    const float* __restrict__ W,
    float* __restrict__ part, int vec) {
  __shared__ float As[16][128];
  __shared__ float Ws[16][64];
  __shared__ int tb_s[33];
  __shared__ int bs_s[33];
  const int tid = threadIdx.x;
  if (tid <= K) { tb_s[tid] = tileBase[tid]; bs_s[tid] = base[tid]; }
  __syncthreads();
  const int totTiles = tb_s[K];
  const int tr = (tid >> 4) << 3;
  const int tc = (tid & 15) << 2;
  const int r2 = tid & 127;
  const int half = tid >> 7;
  const int cw = tid & 63;
  const int cbw = (tid >> 6) << 2;
  const int CB = (Cin + 15) >> 4;
  for (int t = blockIdx.x; t < totTiles; t += gridDim.x) {
    int k = 0;
    while (tb_s[k + 1] <= t) ++k;
    const int cntk = bs_s[k + 1] - bs_s[k];
    const int r0 = (t - tb_s[k]) << 7;
    const int slot = r0 + r2;
    long arow = -1;
    if (slot < cntk) arow = nmap[(long)dst[bs_s[k] + slot] * K + k];
    const float* Asrc = A + (arow < 0 ? 0 : arow) * lda + aoff + half * 8;
    float acc[8][4] = {{0.f}};
    float pa[8], pw[4];
    auto fetch = [&](int cblk) {
      int c0 = cblk * 16;
      if (vec && arow >= 0 && c0 + half * 8 + 8 <= Cin) {
        float4 v0 = *(const float4*)(Asrc + c0);
        float4 v1 = *(const float4*)(Asrc + c0 + 4);
        pa[0] = v0.x; pa[1] = v0.y; pa[2] = v0.z; pa[3] = v0.w;
        pa[4] = v1.x; pa[5] = v1.y; pa[6] = v1.z; pa[7] = v1.w;
      } else {
#pragma unroll
        for (int i = 0; i < 8; ++i) {
          int ci = c0 + half * 8 + i;
          pa[i] = (arow >= 0 && ci < Cin) ? Asrc[c0 + i] : 0.f;
        }
      }
      const float* wsrc = W + ((long)k * Cin + c0 + cbw) * 64 + cw;
#pragma unroll
      for (int i = 0; i < 4; ++i) {
        int ci = c0 + cbw + i;
        pw[i] = (ci < Cin) ? wsrc[(long)i * 64] : 0.f;
      }
    };
    fetch(0);
    for (int cb = 0; cb < CB; ++cb) {
#pragma unroll
      for (int i = 0; i < 8; ++i) As[half * 8 + i][r2] = pa[i];
#pragma unroll
      for (int i = 0; i < 4; ++i) Ws[cbw + i][cw] = pw[i];
      __syncthreads();
      if (cb + 1 < CB) fetch(cb + 1);
#pragma unroll
      for (int kk = 0; kk < 16; ++kk) {
        float a[8], b[4];
#pragma unroll
        for (int i = 0; i < 8; ++i) a[i] = As[kk][tr + i];
#pragma unroll
        for (int j = 0; j < 4; ++j) b[j] = Ws[kk][tc + j];
#pragma unroll
        for (int i = 0; i < 8; ++i)
#pragma unroll
          for (int j = 0; j < 4; ++j) acc[i][j] += a[i] * b[j];
      }
      __syncthreads();
    }
#pragma unroll
    for (int i = 0; i < 8; ++i) {
      int gslot = r0 + tr + i;
      if (gslot < cntk) {
        float4 v = make_float4(acc[i][0], acc[i][1], acc[i][2], acc[i][3]);
        *(float4*)(part + (long)(bs_s[k] + gslot) * 64 + tc) = v;
      }
    }
  }
}

// ---------------------------------------------------------------------------
// K_RED: per-row gather-reduce of partials.  Wave per row, lane = channel.
// ---------------------------------------------------------------------------
__global__ __launch_bounds__(256) void k_red(
    const float* __restrict__ part, const int* __restrict__ rp,
    const int* __restrict__ rmap, float* __restrict__ out, int ldo, int M) {
  int wid = blockIdx.x * 4 + (threadIdx.x >> 6);
  int lane = threadIdx.x & 63;
  if (wid >= M) return;
  int j0 = rp[wid], j1 = rp[wid + 1];
  float a0 = 0.f, a1 = 0.f;
  int j = j0;
  for (; j + 2 <= j1; j += 2) {
    a0 += part[(long)rmap[j] * 64 + lane];
    a1 += part[(long)rmap[j + 1] * 64 + lane];
  }
  if (j < j1) a0 += part[(long)rmap[j] * 64 + lane];
  out[(long)wid * ldo + lane] = a0 + a1;
}

// ---------------------------------------------------------------------------
// K2: bf16 MFMA gathered sparse-conv (heads; dense over K).
// ---------------------------------------------------------------------------
#define K2_SA 72
__global__ __launch_bounds__(256) void k2_conv(
    const u16* __restrict__ A, int lda,
    const int* __restrict__ nmap, int K,
    const u16* __restrict__ WT, int WTR, int CP,
    int Cout,
    const float* __restrict__ bias,
    float* __restrict__ of, int ldo,
    u16* __restrict__ ob, int ldb,
    int M) {
  __shared__ __align__(16) u16 As[128 * K2_SA];
  __shared__ __align__(16) u16 Ws[192 * K2_SA];
  const int tid = threadIdx.x;
  const int m0 = blockIdx.x * 128;
  const int n0 = blockIdx.y * 192;
  const int lane = tid & 63;
  const int w = tid >> 6;
  const int wr = w >> 1, wc = w & 1;
  const int ln = lane & 15, qd = lane >> 4;
  int Cb = Cout - n0; if (Cb > 192) Cb = 192;
  int NTT = (Cb + 15) >> 4;
  int NTw = NTT - wc * 6;
  if (NTw < 0) NTw = 0;
  if (NTw > 6) NTw = 6;
  const int NSB = CP >> 6;
  const int T = K * NSB;
  const int ar = tid & 127;
  const int as0 = tid >> 7;

  uint4 pa[4], pw[6];
  auto fetch = [&](int k, int sb) {
    int m = m0 + ar;
    int idx = (m < M) ? (nmap ? nmap[(long)m * K + k] : m) : -1;
    const u16* src = A + (long)idx * lda + sb * 64;
#pragma unroll
    for (int i = 0; i < 4; ++i) {
      int s = as0 + 2 * i;
      int ci = sb * 64 + s * 8;
      uint4 v = make_uint4(0u, 0u, 0u, 0u);
      if (idx >= 0 && ci + 8 <= lda) v = *(const uint4*)(src + s * 8);
      pa[i] = v;
    }
    const u16* wk = WT + (long)k * WTR * CP + sb * 64;
#pragma unroll
    for (int i = 0; i < 6; ++i) {
      int id = tid + 256 * i;
      int co = id >> 3, s = id & 7;
      int cog = n0 + co;
      uint4 v = make_uint4(0u, 0u, 0u, 0u);
      if (cog < WTR) v = *(const uint4*)(wk + (long)cog * CP + s * 8);
      pw[i] = v;
    }
  };

  f32x4 acc[4][6];
  f32x4 zero = {0.f, 0.f, 0.f, 0.f};
#pragma unroll
  for (int i = 0; i < 4; ++i)
#pragma unroll
    for (int j = 0; j < 6; ++j) acc[i][j] = zero;

  fetch(0, 0);
  int kc = 0, sc = 0;
  for (int t = 0; t < T; ++t) {
#pragma unroll
    for (int i = 0; i < 4; ++i)
      *(uint4*)&As[ar * K2_SA + (as0 + 2 * i) * 8] = pa[i];
#pragma unroll
    for (int i = 0; i < 6; ++i) {
      int id = tid + 256 * i;
      *(uint4*)&Ws[(id >> 3) * K2_SA + (id & 7) * 8] = pw[i];
    }
    __syncthreads();
    int sn = sc + 1, kn = kc;
    if (sn == NSB) { sn = 0; kn++; }
    if (kn < K) fetch(kn, sn);
    if (NTw > 0) {
#pragma unroll
      for (int ch = 0; ch < 2; ++ch) {
        int koff = ch * 32 + qd * 8;
        bf16x8 a[4];
#pragma unroll
        for (int st = 0; st < 4; ++st)
          a[st] = *(const bf16x8*)&As[(wr * 64 + st * 16 + ln) * K2_SA + koff];
#pragma unroll
        for (int nt = 0; nt < 6; ++nt) {
          if (nt < NTw) {
            bf16x8 b = *(const bf16x8*)&Ws[(wc * 96 + nt * 16 + ln) * K2_SA + koff];
#pragma unroll
            for (int st = 0; st < 4; ++st)
              acc[st][nt] = __builtin_amdgcn_mfma_f32_16x16x32_bf16(a[st], b, acc[st][nt], 0, 0, 0);
          }
        }
      }
    }
    __syncthreads();
    sc = sn; kc = kn;
  }
#pragma unroll
  for (int nt = 0; nt < 6; ++nt) {
    if (nt >= NTw) continue;
    int col = n0 + wc * 96 + nt * 16 + ln;
    if (col >= Cout) continue;
    float bv = bias ? bias[col] : 0.f;
#pragma unroll
    for (int st = 0; st < 4; ++st) {
#pragma unroll
      for (int i = 0; i < 4; ++i) {
        int m = m0 + wr * 64 + st * 16 + qd * 4 + i;
        if (m < M) {
          float v = acc[st][nt][i] + bv;
          if (of) of[(long)m * ldo + col] = v;
          if (ob) ob[(long)m * ldb + col] = f2bf(v);
        }
      }
    }
  }
}

// ---------------------------------------------------------------------------
// stats: per-(batch,channel) sum / sumsq (+count) for instance norm.
// ---------------------------------------------------------------------------
__global__ __launch_bounds__(256) void k_stats(
    const float* __restrict__ x, int ld, int M, int C,
    const int* __restrict__ bidx, float* __restrict__ st) {
  __shared__ float ssum[2][192];
  __shared__ float ssq[2][192];
  __shared__ float scnt[2];
  for (int i = threadIdx.x; i < 384; i += 256) {
    ((float*)ssum)[i] = 0.f;
    ((float*)ssq)[i] = 0.f;
  }
  if (threadIdx.x < 2) scnt[threadIdx.x] = 0.f;
  __syncthreads();
  const int CV = C >> 2;
  const int RG = 256 / CV;
  const int tid = threadIdx.x;
  const int c4 = tid % CV;
  const int rg = tid / CV;
  int rpb = (M + gridDim.x - 1) / gridDim.x;
  int r0 = blockIdx.x * rpb;
  int r1 = r0 + rpb;
  if (r1 > M) r1 = M;
  if (rg < RG) {
    float s0[4] = {0.f, 0.f, 0.f, 0.f}, q0[4] = {0.f, 0.f, 0.f, 0.f};
    float s1[4] = {0.f, 0.f, 0.f, 0.f}, q1[4] = {0.f, 0.f, 0.f, 0.f};
    float n0 = 0.f, n1 = 0.f;
    for (int rr = r0 + rg; rr < r1; rr += RG) {
      int b = bidx[rr];
      float4 v = *(const float4*)&x[(long)rr * ld + c4 * 4];
      const float* vp = &v.x;
      if (b == 0) {
#pragma unroll
        for (int j = 0; j < 4; ++j) { s0[j] += vp[j]; q0[j] += vp[j] * vp[j]; }
        n0 += 1.f;
      } else {
#pragma unroll
        for (int j = 0; j < 4; ++j) { s1[j] += vp[j]; q1[j] += vp[j] * vp[j]; }
        n1 += 1.f;
      }
    }
#pragma unroll
    for (int j = 0; j < 4; ++j) {
      if (s0[j] != 0.f || q0[j] != 0.f) {
        atomicAdd(&ssum[0][c4 * 4 + j], s0[j]);
        atomicAdd(&ssq[0][c4 * 4 + j], q0[j]);
      }
      if (s1[j] != 0.f || q1[j] != 0.f) {
        atomicAdd(&ssum[1][c4 * 4 + j], s1[j]);
        atomicAdd(&ssq[1][c4 * 4 + j], q1[j]);
      }
    }
    if (c4 == 0) {
      if (n0 != 0.f) atomicAdd(&scnt[0], n0);
      if (n1 != 0.f) atomicAdd(&scnt[1], n1);
    }
  }
  __syncthreads();
  for (int i = threadIdx.x; i < C; i += 256) {
    if (ssum[0][i] != 0.f || ssq[0][i] != 0.f) {
      atomicAdd(&st[i], ssum[0][i]);
      atomicAdd(&st[C + i], ssq[0][i]);
    }
    if (ssum[1][i] != 0.f || ssq[1][i] != 0.f) {
      atomicAdd(&st[2 * C + i], ssum[1][i]);
      atomicAdd(&st[3 * C + i], ssq[1][i]);
    }
  }
  if (threadIdx.x == 0) {
    if (scnt[0] != 0.f) atomicAdd(&st[4 * C], scnt[0]);
    if (scnt[1] != 0.f) atomicAdd(&st[4 * C + 1], scnt[1]);
  }
}

// ---------------------------------------------------------------------------
// apply: v = (x - mean)*rsqrt(var+eps) [+ res] [relu] -> optional f32 / bf16
// ---------------------------------------------------------------------------
__global__ __launch_bounds__(256) void k_apply(
    const float* __restrict__ x, int ldx, int M, int C,
    const int* __restrict__ bidx, const float* __restrict__ st,
    const float* __restrict__ res, int ldr, int relu,
    float* __restrict__ of, int ldo, u16* __restrict__ ob, int ldb) {
  __shared__ float mean_s[2][192];
  __shared__ float inv_s[2][192];
  for (int j = threadIdx.x; j < 2 * C; j += 256) {
    int b = (j >= C) ? 1 : 0;
    int c = j - b * C;
    float cnt = st[4 * C + b];
    float mean = st[b * 2 * C + c] / cnt;
    float var = st[b * 2 * C + C + c] / cnt - mean * mean;
    mean_s[b][c] = mean;
    inv_s[b][c] = 1.f / sqrtf(fmaxf(var, 0.f) + 1e-5f);
  }
  __syncthreads();
  const int CV = C >> 2;
  long total = (long)M * CV;
  long stride = (long)gridDim.x * 256;
  for (long i = (long)blockIdx.x * 256 + threadIdx.x; i < total; i += stride) {
    int rr = (int)(i / CV);
    int c4 = (int)(i - (long)rr * CV);
    int b = bidx[rr];
    float4 v = *(const float4*)&x[(long)rr * ldx + c4 * 4];
    const float* vp = &v.x;
    float o[4];
#pragma unroll
    for (int j = 0; j < 4; ++j) {
      int c = c4 * 4 + j;
      o[j] = (vp[j] - mean_s[b][c]) * inv_s[b][c];
    }
    if (res) {
      float4 rv = *(const float4*)&res[(long)rr * ldr + c4 * 4];
      const float* rp = &rv.x;
#pragma unroll
      for (int j = 0; j < 4; ++j) o[j] += rp[j];
    }
    if (relu) {
#pragma unroll
      for (int j = 0; j < 4; ++j) o[j] = fmaxf(o[j], 0.f);
    }
    if (of) {
      float4 ov = make_float4(o[0], o[1], o[2], o[3]);
      *(float4*)&of[(long)rr * ldo + c4 * 4] = ov;
    }
    if (ob) {
      ushort4 u;
      u.x = f2bf(o[0]); u.y = f2bf(o[1]); u.z = f2bf(o[2]); u.w = f2bf(o[3]);
      *(ushort4*)&ob[(long)rr * ldb + c4 * 4] = u;
    }
  }
}

// proxy = sparse @ W_occ + b_occ ; mask = proxy > 0 ; sp = mask ? sparse : 0
__global__ __launch_bounds__(256) void k_mask(
    const float* __restrict__ sp, const float* __restrict__ Wocc,
    const float* __restrict__ bocc, float* __restrict__ proxy,
    float* __restrict__ catf, u16* __restrict__ catb, int M) {
  int r = blockIdx.x * 4 + (threadIdx.x >> 6);
  int lane = threadIdx.x & 63;
  if (r >= M) return;
  float v0 = sp[(long)r * 128 + lane];
  float v1 = sp[(long)r * 128 + 64 + lane];
  float s = v0 * Wocc[lane] + v1 * Wocc[64 + lane];
  for (int off = 32; off > 0; off >>= 1) s += __shfl_down(s, off);
  s = __shfl(s, 0);
  float p = s + bocc[0];
  if (lane == 0) proxy[r] = p;
  bool m = p > 0.0f;
  float w0 = m ? v0 : 0.f, w1 = m ? v1 : 0.f;
  catf[(long)r * 192 + 64 + lane] = w0;
  catf[(long)r * 192 + 128 + lane] = w1;
  catb[(long)r * 192 + 64 + lane] = f2bf(w0);
  catb[(long)r * 192 + 128 + lane] = f2bf(w1);
}

// copy cat -> full[:,0:192] and zero full[:,229:232]
__global__ __launch_bounds__(256) void k_full(
    const u16* __restrict__ catb, u16* __restrict__ full, int M) {
  long total = (long)M * 195;
  long stride = (long)gridDim.x * 256;
  for (long i = (long)blockIdx.x * 256 + threadIdx.x; i < total; i += stride) {
    int r = (int)(i / 195);
    int j = (int)(i - (long)r * 195);
    if (j < 192)
      full[(long)r * 232 + j] = catb[(long)r * 192 + j];
    else
      full[(long)r * 232 + 229 + (j - 192)] = 0;
  }
}

// weight convert: src f32 [K][Cin][Cout] -> dst bf16 transposed [K][WTR][CP]
__global__ __launch_bounds__(256) void k_wconv(
    const float* __restrict__ src, u16* __restrict__ dst,
    int K, int Cin, int Cout, int WTR, int CP) {
  long total = (long)K * WTR * CP;
  long stride = (long)gridDim.x * 256;
  for (long i = (long)blockIdx.x * 256 + threadIdx.x; i < total; i += stride) {
    int ci = (int)(i % CP);
    long t = i / CP;
    int co = (int)(t % WTR);
    int k = (int)(t / WTR);
    float v = 0.f;
    if (ci < Cin && co < Cout) v = src[((long)k * Cin + ci) * Cout + co];
    dst[i] = f2bf(v);
  }
}

// ---------------------------------------------------------------------------
extern "C" void kernel_launch(void* const* d_in, const int* in_sizes, int n_in,
                              void* d_out, int out_size, void* d_ws, size_t ws_size,
                              hipStream_t stream) {
  const float* features = (const float*)d_in[0];
  const int* nmap1 = (const int*)d_in[1];
  const int* cmap = (const int*)d_in[2];
  const int* nmap2 = (const int*)d_in[3];
  const int* b1 = (const int*)d_in[4];
  const int* b2 = (const int*)d_in[5];
  const int* b3 = (const int*)d_in[6];
  const float* W_d1 = (const float*)d_in[7];
  const float* W_d2 = (const float*)d_in[8];
  const float* Wd_d = (const float*)d_in[9];
  const float* W_f1 = (const float*)d_in[11];
  const float* W_f2 = (const float*)d_in[12];
  const float* Wd_f = (const float*)d_in[13];
  const float* W_i1 = (const float*)d_in[15];
  const float* W_i2 = (const float*)d_in[16];
  const float* Wd_i = (const float*)d_in[17];
  const float* W_e1a = (const float*)d_in[19];
  const float* W_e1b = (const float*)d_in[20];
  const float* W_ed = (const float*)d_in[21];
  const float* W_e2a = (const float*)d_in[23];
  const float* W_e2b = (const float*)d_in[24];
  const float* W_sub = (const float*)d_in[25];
  const float* b_sub = (const float*)d_in[26];
  const float* W_occ = (const float*)d_in[27];
  const float* b_occ = (const float*)d_in[28];
  const float* W_pi1 = (const float*)d_in[29];
  const float* W_pi2 = (const float*)d_in[30];
  const float* W_pi3 = (const float*)d_in[31];
  const float* b_pi3 = (const float*)d_in[32];
  const float* W_ps1 = (const float*)d_in[33];
  const float* W_ps2 = (const float*)d_in[34];
  const float* W_ps3 = (const float*)d_in[35];
  const float* b_ps3 = (const float*)d_in[36];
  const float* W_t = (const float*)d_in[37];

  const int N1 = in_sizes[4];
  const int N2 = in_sizes[5];

  // ---- workspace layout ----
  char* base = (char*)d_ws;
  size_t off = 0;
  auto alloc = [&](size_t bytes) -> void* {
    void* r = base + off;
    off += (bytes + 255) & ~(size_t)255;
    return r;
  };
  float* x = (float*)alloc((size_t)N1 * 192 * 4);
  float* T = (float*)alloc((size_t)N1 * 256 * 4);
  float* Bq1 = T;
  float* Bq2 = T + (size_t)N1 * 64;
  float* Bq3 = T + (size_t)N1 * 128;
  float* Bq4 = T + (size_t)N1 * 192;
  float* t192 = T;
  // NOTE: part aliases catb..WT region (only live during trunk/encoder convs,
  // which finish before catb/hb/pib/fullb/spf/WT* are first written).
  u16* catb = (u16*)alloc((size_t)N2 * 192 * 2);
  u16* hb = (u16*)alloc((size_t)N2 * 192 * 2);
  u16* pib = (u16*)alloc((size_t)N2 * 192 * 2);
  u16* fullb = (u16*)alloc((size_t)N2 * 232 * 2);
  float* spf = (float*)alloc((size_t)N2 * 128 * 4);
  u16* WTpi1 = (u16*)alloc((size_t)27 * 192 * 192 * 2);
  u16* WTpi2 = (u16*)alloc((size_t)27 * 192 * 192 * 2);
  u16* WTps1 = (u16*)alloc((size_t)27 * 192 * 192 * 2);
  u16* WTps2 = (u16*)alloc((size_t)27 * 192 * 192 * 2);
  u16* WTpi3 = (u16*)alloc((size_t)27 * 32 * 192 * 2);
  u16* WTps3 = (u16*)alloc((size_t)27 * 32 * 192 * 2);
  u16* WTt = (u16*)alloc((size_t)8 * 64 * 256 * 2);
  float* stats = (float*)alloc((size_t)19 * 772 * 4);
  // sparse-conv index structures
  int* rp1 = (int*)alloc((size_t)(N1 + 1) * 4);
  int* rpc = (int*)alloc((size_t)(N2 + 1) * 4);
  int* rp2 = (int*)alloc((size_t)(N2 + 1) * 4);
  int* meta = (int*)alloc((size_t)3 * 256 * 4);
  int* bscr = (int*)alloc((size_t)2048 * 4);
  const int cap1 = (int)((long)N1 * 26 / 10) + 1024;  // ~2.6/row, mean 1.93
  const int capc = N1 + 256;                          // exactly N1 pairs
  const int cap2 = (int)((long)N2 * 9) + 1024;        // ~9/row, mean ~7.5
  int* dst1 = (int*)alloc((size_t)cap1 * 4);
  int* rmap1 = (int*)alloc((size_t)cap1 * 4);
  int* dstc = (int*)alloc((size_t)capc * 4);
  int* rmapc = (int*)alloc((size_t)capc * 4);
  int* dst2 = (int*)alloc((size_t)cap2 * 4);
  int* rmap2 = (int*)alloc((size_t)cap2 * 4);
  if (off > ws_size) return;  // workspace too small: bail (will fail loudly)

  float* part = (float*)catb;  // alias (see note above); cap2*256 B fits region
  float* catf = x;             // alias: x dead once encoder residuals built
  float* dout = (float*)d_out;
  float* out0 = dout;
  float* proxyp = dout + (size_t)N2 * 512;
  float* pip = proxyp + N2;
  float* psp = pip + (size_t)N2 * 17;

  hipMemsetAsync(stats, 0, (size_t)19 * 772 * 4, stream);
  hipMemsetAsync(meta, 0, (size_t)3 * 256 * 4, stream);

  // ---- sparse index build (per map): k-lists + row CSR (no data atomics) ----
  auto build = [&](const int* nm, int M, int K, int* mt, int* rp, int* dst, int* rmap) {
    int nb = cdiv(M, 256);  // requires M <= 262144
    k_cnt<<<nb, 256, 0, stream>>>(nm, K, M, mt);
    k_cscan<<<1, 64, 0, stream>>>(mt, K, mt + 32, mt + 65, mt + 98);
    k_rp1<<<nb, 256, 0, stream>>>(nm, K, M, rp, bscr);
    k_rp2<<<1, 1024, 0, stream>>>(bscr, nb, bscr + 1024, rp + M);
    k_fill<<<nb, 256, 0, stream>>>(nm, K, M, mt + 32, mt + 98, bscr + 1024, rp, dst, rmap);
  };
  int* mt1 = meta;
  int* mtc = meta + 256;
  int* mt2 = meta + 512;
  build(nmap1, N1, 27, mt1, rp1, dst1, rmap1);
  build(cmap, N2, 8, mtc, rpc, dstc, rmapc);
  build(nmap2, N2, 27, mt2, rp2, dst2, rmap2);

  const int SG = 1024;
  const int AG = 1024;
  const int GG = 2048;  // gather-GEMM grid (grid-strided over tiles)
  int slot = 0;

  // sparse conv = gather-GEMM into part + per-row reduce
  auto sconv = [&](const float* Ain, int lda_, int aoff_, int Cin_,
                   const int* nm, int K_, int* mt, int* dst, int* rmap, int* rp,
                   const float* W_, float* out_, int M_, int vec_) {
    k1g_conv<<<GG, 256, 0, stream>>>(Ain, lda_, aoff_, Cin_, nm, K_,
                                     dst, mt + 32, mt + 65, W_, part, vec_);
    k_red<<<cdiv(M_, 4), 256, 0, stream>>>(part, rp, rmap, out_, 64, M_);
  };

  struct Br { int aoff, Cin; const float *W1, *W2, *Wd; };
  Br brs[3] = {{0, 2, W_d1, W_d2, Wd_d},
               {2, 80, W_f1, W_f2, Wd_f},
               {82, 17, W_i1, W_i2, Wd_i}};

  // ---- fine branches (fp32 trunk) ----
  for (int b = 0; b < 3; ++b) {
    const int Cin = brs[b].Cin;
    // dense residual: inorm(f @ Wd)
    k1_conv<<<dim3(cdiv(N1, 128), 1), 256, 0, stream>>>(
        features, 99, brs[b].aoff, Cin, nullptr, 1, brs[b].Wd, 64, nullptr, Bq1, 64, N1, 0);
    k_stats<<<SG, 256, 0, stream>>>(Bq1, 64, N1, 64, b1, stats + slot * 772);
    k_apply<<<AG, 256, 0, stream>>>(Bq1, 64, N1, 64, b1, stats + slot * 772,
                                    nullptr, 0, 0, Bq3, 64, nullptr, 0);
    slot++;
    // conv1 (all offsets incl self) + inorm + relu
    sconv(features, 99, brs[b].aoff, Cin, nmap1, 27, mt1, dst1, rmap1, rp1,
          brs[b].W1, Bq1, N1, 0);
    k_stats<<<SG, 256, 0, stream>>>(Bq1, 64, N1, 64, b1, stats + slot * 772);
    k_apply<<<AG, 256, 0, stream>>>(Bq1, 64, N1, 64, b1, stats + slot * 772,
                                    nullptr, 0, 1, Bq2, 64, nullptr, 0);
    slot++;
    // conv2 + inorm + res + relu -> x[:, b*64 : b*64+64]
    sconv(Bq2, 64, 0, 64, nmap1, 27, mt1, dst1, rmap1, rp1,
          brs[b].W2, Bq4, N1, 1);
    k_stats<<<SG, 256, 0, stream>>>(Bq4, 64, N1, 64, b1, stats + slot * 772);
    k_apply<<<AG, 256, 0, stream>>>(Bq4, 64, N1, 64, b1, stats + slot * 772,
                                    Bq3, 64, 1, x + b * 64, 192, nullptr, 0);
    slot++;
  }

  // ---- encoder (fp32 trunk) ----
  sconv(x, 192, 0, 192, cmap, 8, mtc, dstc, rmapc, rpc, W_e1a, Bq1, N2, 1);
  k_stats<<<SG, 256, 0, stream>>>(Bq1, 64, N2, 64, b2, stats + slot * 772);
  k_apply<<<AG, 256, 0, stream>>>(Bq1, 64, N2, 64, b2, stats + slot * 772,
                                  nullptr, 0, 1, Bq2, 64, nullptr, 0);
  slot++;
  sconv(Bq2, 64, 0, 64, nmap2, 27, mt2, dst2, rmap2, rp2, W_e1b, Bq4, N2, 1);
  k_stats<<<SG, 256, 0, stream>>>(Bq4, 64, N2, 64, b2, stats + slot * 772);
  int sl_e1b = slot; slot++;
  sconv(x, 192, 0, 192, cmap, 8, mtc, dstc, rmapc, rpc, W_ed, Bq1, N2, 1);
  k_stats<<<SG, 256, 0, stream>>>(Bq1, 64, N2, 64, b2, stats + slot * 772);
  k_apply<<<AG, 256, 0, stream>>>(Bq1, 64, N2, 64, b2, stats + slot * 772,
                                  nullptr, 0, 0, Bq3, 64, nullptr, 0);
  slot++;
  k_apply<<<AG, 256, 0, stream>>>(Bq4, 64, N2, 64, b2, stats + sl_e1b * 772,
                                  Bq3, 64, 1, Bq2, 64, nullptr, 0);
  sconv(Bq2, 64, 0, 64, nmap2, 27, mt2, dst2, rmap2, rp2, W_e2a, Bq1, N2, 1);
  k_stats<<<SG, 256, 0, stream>>>(Bq1, 64, N2, 64, b2, stats + slot * 772);
  k_apply<<<AG, 256, 0, stream>>>(Bq1, 64, N2, 64, b2, stats + slot * 772,
                                  nullptr, 0, 1, Bq3, 64, nullptr, 0);
  slot++;
  sconv(Bq3, 64, 0, 64, nmap2, 27, mt2, dst2, rmap2, rp2, W_e2b, Bq4, N2, 1);
  // part is DEAD from here on; catb..WT region free for its real owners.
  k_stats<<<SG, 256, 0, stream>>>(Bq4, 64, N2, 64, b2, stats + slot * 772);
  k_apply<<<AG, 256, 0, stream>>>(Bq4, 64, N2, 64, b2, stats + slot * 772,
                                  Bq2, 64, 1, catf, 192, catb, 192);
  slot++;

  // ---- head weight conversion (AFTER part is dead: WT* overlap part) ----
  k_wconv<<<256, 256, 0, stream>>>(W_pi1, WTpi1, 27, 192, 192, 192, 192);
  k_wconv<<<256, 256, 0, stream>>>(W_pi2, WTpi2, 27, 192, 192, 192, 192);
  k_wconv<<<256, 256, 0, stream>>>(W_ps1, WTps1, 27, 192, 192, 192, 192);
  k_wconv<<<256, 256, 0, stream>>>(W_ps2, WTps2, 27, 192, 192, 192, 192);
  k_wconv<<<256, 256, 0, stream>>>(W_pi3, WTpi3, 27, 192, 17, 32, 192);
  k_wconv<<<256, 256, 0, stream>>>(W_ps3, WTps3, 27, 192, 20, 32, 192);
  k_wconv<<<256, 256, 0, stream>>>(W_t, WTt, 8, 229, 64, 64, 256);

  // ---- sparse / proxy / mask (fp32) ----
  k1_conv<<<dim3(cdiv(N2, 128), 2), 256, 0, stream>>>(
      catf, 192, 0, 64, nullptr, 1, W_sub, 128, b_sub, spf, 128, N2, 1);
  k_mask<<<cdiv(N2, 4), 256, 0, stream>>>(spf, W_occ, b_occ, proxyp, catf, catb, N2);
  k_full<<<1024, 256, 0, stream>>>(catb, fullb, N2);

  // ---- heads (bf16 MFMA, dense over 27) ----
  const u16* WT1[2] = {WTpi1, WTps1};
  const u16* WT2[2] = {WTpi2, WTps2};
  const u16* WT3[2] = {WTpi3, WTps3};
  const float* b3v[2] = {b_pi3, b_ps3};
  float* outh[2] = {pip, psp};
  int co3[2] = {17, 20};
  int ld3[2] = {17, 20};
  int foff[2] = {192, 209};
  for (int h = 0; h < 2; ++h) {
    k2_conv<<<dim3(cdiv(N2, 128), 1), 256, 0, stream>>>(
        catb, 192, nmap2, 27, WT1[h], 192, 192, 192, nullptr, t192, 192, nullptr, 0, N2);
    k_stats<<<SG, 256, 0, stream>>>(t192, 192, N2, 192, b2, stats + slot * 772);
    k_apply<<<AG, 256, 0, stream>>>(t192, 192, N2, 192, b2, stats + slot * 772,
                                    nullptr, 0, 1, nullptr, 0, hb, 192);
    slot++;
    k2_conv<<<dim3(cdiv(N2, 128), 1), 256, 0, stream>>>(
        hb, 192, nmap2, 27, WT2[h], 192, 192, 192, nullptr, t192, 192, nullptr, 0, N2);
    k_stats<<<SG, 256, 0, stream>>>(t192, 192, N2, 192, b2, stats + slot * 772);
    k_apply<<<AG, 256, 0, stream>>>(t192, 192, N2, 192, b2, stats + slot * 772,
                                    catf, 192, 1, nullptr, 0, pib, 192);
    slot++;
    k2_conv<<<dim3(cdiv(N2, 128), 1), 256, 0, stream>>>(
        pib, 192, nmap2, 27, WT3[h], 32, 192, co3[h], b3v[h],
        outh[h], ld3[h], fullb + foff[h], 232, N2);
  }

  // ---- final einsum as ONE GEMM ----
  k2_conv<<<dim3(cdiv(N2, 128), 3), 256, 0, stream>>>(
      fullb, 232, nullptr, 1, WTt, 512, 256, 512, nullptr,
      out0, 512, nullptr, 0, N2);

  // final inorm + relu over (N2*8, 64) rows with b3, in place in d_out
  k_stats<<<SG, 256, 0, stream>>>(out0, 64, N2 * 8, 64, b3, stats + slot * 772);
  k_apply<<<AG, 256, 0, stream>>>(out0, 64, N2 * 8, 64, b3, stats + slot * 772,
                                  nullptr, 0, 1, out0, 64, nullptr, 0);
}